// Round 11
// baseline (447.467 us; speedup 1.0000x reference)
//
#include <hip/hip_runtime.h>
#include <hip/hip_bf16.h>

#define BATCH 16
#define SEQ 8192
#define CH 32
#define NB 24

typedef __attribute__((ext_vector_type(8))) short short8;
typedef __attribute__((ext_vector_type(4))) short short4v;
typedef __attribute__((ext_vector_type(4))) float f32x4;

__device__ __forceinline__ unsigned short f2bf(float x) {
    __hip_bfloat16 b = __float2bfloat16(x);   // RNE
    unsigned short u;
    __builtin_memcpy(&u, &b, 2);
    return u;
}
__device__ __forceinline__ float bf2f(unsigned short h) {
    return __uint_as_float(((unsigned int)h) << 16);
}
__device__ __forceinline__ float rcp_fast(float x) { return __builtin_amdgcn_rcpf(x); }

// tanh(f)*sigmoid(g) with a single reciprocal
__device__ __forceinline__ float gate_fn(float f, float g) {
    float ef = __expf(-2.0f * fabsf(f));
    float eg = __expf(-g);
    float num = 1.0f - ef;
    float den = (1.0f + ef) * (1.0f + eg);
    return copysignf(num * rcp_fast(den), f);
}

__device__ __forceinline__ void split2(float v, unsigned short& h, unsigned short& l) {
    h = f2bf(v);
    l = f2bf(v - bf2f(h));
}

// ============ prep (256 thr/block): bf16 hi/lo weights in MFMA frag order,
// conv rows sigma-permuted (r10: gated C-layout == skip B-layout). Zeros pooled.
__global__ __launch_bounds__(256) void k_prep(const float* __restrict__ Wd,
                                              const float* __restrict__ bd,
                                              const float* __restrict__ W1,
                                              const float* __restrict__ b1,
                                              unsigned short* __restrict__ stream,
                                              float* __restrict__ pooled) {
    int i = blockIdx.x;
    int tid = threadIdx.x;
    int l = tid & 63, q4 = tid >> 6;
    int p = l & 15, h4 = l >> 4;
    const float* wd  = Wd + (size_t)i * 64 * 64;
    const float* w1  = W1 + (size_t)i * 1024;
    const float* bdp = bd + (size_t)i * 64;
    const float* b1p = b1 + (size_t)i * 32;
    unsigned short* out = stream + (size_t)i * (28672 / 2);

    for (int g = blockIdx.x * 256 + tid; g < BATCH * CH * 4; g += NB * 256)
        pooled[g] = 0.0f;

    {   // conv A-frags: quarter q4 = tile rt
        int rt = q4;
        int is_g = (rt >= 2) ? 32 : 0;
        int ch = 8 * (p >> 2) + 4 * (rt & 1) + (p & 3);     // sigma(rt, p)
        int row = ch + is_g;
        for (int q = 0; q < 2; ++q) {
            int slot = rt * 2 + q;
            for (int j = 0; j < 8; ++j) {
                int k = 32 * q + 8 * h4 + j;
                int c = k & 31, tap = k >> 5;
                float w = wd[row * 64 + c * 2 + tap];
                unsigned short hi = f2bf(w);
                out[(size_t)slot * 512 + l * 8 + j] = hi;
                out[(size_t)(8 + slot) * 512 + l * 8 + j] = f2bf(w - bf2f(hi));
            }
        }
    }
    if (q4 < 2) {   // skip A-frags (natural order)
        int rt2 = q4;
        for (int j = 0; j < 8; ++j) {
            int o = 16 * rt2 + p, c = 8 * h4 + j;
            float w = w1[o * 32 + c];
            unsigned short hi = f2bf(w);
            out[(size_t)(16 + rt2) * 512 + l * 8 + j] = hi;
            out[(size_t)(18 + rt2) * 512 + l * 8 + j] = f2bf(w - bf2f(hi));
        }
    }
    float* outf = (float*)stream + (size_t)i * (28672 / 4);
    if (q4 == 2) {   // conv biases, sigma-permuted
        for (int rt = 0; rt < 4; ++rt) {
            int is_g = (rt >= 2) ? 32 : 0;
            for (int r = 0; r < 4; ++r)
                outf[(size_t)(20 + rt) * 256 + l * 4 + r] =
                    bdp[8 * h4 + 4 * (rt & 1) + r + is_g];
        }
    }
    if (q4 == 3) {   // skip biases (natural)
        for (int rt2 = 0; rt2 < 2; ++rt2)
            for (int r = 0; r < 4; ++r)
                outf[(size_t)(24 + rt2) * 256 + l * 4 + r] = b1p[16 * rt2 + 4 * h4 + r];
    }
}

// ============ fused 8-layer stack. r11: h in LDS as PRE-SPLIT bf16 hi/lo planes
// (conv B-frags = raw ds_read_b128, no read-side splits; split only at phase-2
// write: 8 split2/s6). Tile OUT=256, worked 512 rows, LDS = 2*512*80 = 81,920 B
// exactly -> 2 blocks/CU, 4 waves/SIMD (the r10 latency diagnosis). 512 thr,
// each wave owns 64 rows (4 s6). Sigma-permuted weights: skip B-frag direct in
// registers. Causal gate on GLOBAL pos (r5). red[] aliased onto dead halo rows.
__global__ __launch_bounds__(512, 4) void k_stack(
        const unsigned short* __restrict__ hin_hi,
        const unsigned short* __restrict__ hin_lo,
        unsigned short* __restrict__ hout_hi,
        unsigned short* __restrict__ hout_lo,
        const float* __restrict__ x,
        const float* __restrict__ W0,
        const float* __restrict__ b0,
        const float* __restrict__ Wf,
        const float* __restrict__ bf,
        float* __restrict__ pooled,
        const unsigned short* __restrict__ wstream,
        int stack) {
    __shared__ __align__(16) unsigned short lhi[512][40];   // 40,960 B
    __shared__ __align__(16) unsigned short llo[512][40];   // 40,960 B  (total 81,920)

    int tid = threadIdx.x;
    int lane = tid & 63, wave = tid >> 6;
    int p = lane & 15, h4 = lane >> 4;
    int bb = blockIdx.x >> 5;                 // 32 tiles per batch
    int T0 = (blockIdx.x & 31) * 256;
    bool first = (stack == 0);
    bool last  = (stack == 2);

    const unsigned short* pin_hi = hin_hi + (size_t)bb * SEQ * CH;
    const unsigned short* pin_lo = hin_lo + (size_t)bb * SEQ * CH;
    unsigned short* pout_hi = hout_hi + (size_t)bb * SEQ * CH;
    unsigned short* pout_lo = hout_lo + (size_t)bb * SEQ * CH;
    const float* px = x + (size_t)bb * SEQ;

    const short8 zero8 = {0, 0, 0, 0, 0, 0, 0, 0};

    // ---- tile load: one row per thread (512 rows, 512 threads)
    {
        int i = tid;
        int t = T0 - 256 + i;
        if (first) {
            if (t >= 0) {
                float xt = px[t];
                float xm = (t > 0) ? px[t - 1] : 0.0f;
#pragma unroll
                for (int c = 0; c < CH; ++c) {
                    float v = W0[c * 2] * xm + W0[c * 2 + 1] * xt + b0[c];
                    unsigned short hh, ll;
                    split2(v, hh, ll);
                    lhi[i][c] = hh;
                    llo[i][c] = ll;
                }
            } else {
#pragma unroll
                for (int k = 0; k < 4; ++k) {
                    *(short8*)&lhi[i][8 * k] = zero8;
                    *(short8*)&llo[i][8 * k] = zero8;
                }
            }
        } else {
            if (t >= 0) {
                const unsigned short* sh = pin_hi + (size_t)t * CH;
                const unsigned short* sl = pin_lo + (size_t)t * CH;
#pragma unroll
                for (int k = 0; k < 4; ++k) {
                    *(short8*)&lhi[i][8 * k] = *(const short8*)(sh + 8 * k);
                    *(short8*)&llo[i][8 * k] = *(const short8*)(sl + 8 * k);
                }
            } else {
#pragma unroll
                for (int k = 0; k < 4; ++k) {
                    *(short8*)&lhi[i][8 * k] = zero8;
                    *(short8*)&llo[i][8 * k] = zero8;
                }
            }
        }
    }
    __syncthreads();

#pragma unroll 1
    for (int l = 0; l < 8; ++l) {
        int dil = 1 << l;
        const unsigned short* frag = wstream + (size_t)(8 * stack + l) * 14336;
        const short8* fs = (const short8*)frag;
        short8 Ah[4][2], Al[4][2], Sh[2], Sl[2];
#pragma unroll
        for (int rt = 0; rt < 4; ++rt)
#pragma unroll
            for (int q = 0; q < 2; ++q) {
                Ah[rt][q] = fs[(rt * 2 + q) * 64 + lane];
                Al[rt][q] = fs[(8 + rt * 2 + q) * 64 + lane];
            }
#pragma unroll
        for (int rt2 = 0; rt2 < 2; ++rt2) {
            Sh[rt2] = fs[(16 + rt2) * 64 + lane];
            Sl[rt2] = fs[(18 + rt2) * 64 + lane];
        }
        const f32x4* ff = (const f32x4*)frag;
        f32x4 bFG[4], bS[2];
#pragma unroll
        for (int rt = 0; rt < 4; ++rt) bFG[rt] = ff[(20 + rt) * 64 + lane];
#pragma unroll
        for (int rt2 = 0; rt2 < 2; ++rt2) bS[rt2] = ff[(24 + rt2) * 64 + lane];

        f32x4 hnew[4][2];

        // ---- phase 1: conv frags are raw b128 reads (pre-split planes)
#pragma unroll
        for (int s6 = 0; s6 < 4; ++s6) {
            int tpos = wave * 64 + s6 * 16 + p;
            int tq = tpos - dil;
            bool ok = (T0 - 256 + tq >= 0);   // causal gate on GLOBAL source pos
            int tqc = (tq > 0) ? tq : 0;

            short8 bh1 = *(const short8*)&lhi[tpos][8 * h4];
            short8 bl1 = *(const short8*)&llo[tpos][8 * h4];
            short8 bh0 = *(const short8*)&lhi[tqc][8 * h4];
            short8 bl0 = *(const short8*)&llo[tqc][8 * h4];
            if (!ok) { bh0 = zero8; bl0 = zero8; }

            f32x4 acc[4];
#pragma unroll
            for (int rt = 0; rt < 4; ++rt) {
                f32x4 a = bFG[rt];
                a = __builtin_amdgcn_mfma_f32_16x16x32_bf16(Ah[rt][0], bh0, a, 0, 0, 0);
                a = __builtin_amdgcn_mfma_f32_16x16x32_bf16(Ah[rt][1], bh1, a, 0, 0, 0);
                a = __builtin_amdgcn_mfma_f32_16x16x32_bf16(Ah[rt][0], bl0, a, 0, 0, 0);
                a = __builtin_amdgcn_mfma_f32_16x16x32_bf16(Ah[rt][1], bl1, a, 0, 0, 0);
                a = __builtin_amdgcn_mfma_f32_16x16x32_bf16(Al[rt][0], bh0, a, 0, 0, 0);
                a = __builtin_amdgcn_mfma_f32_16x16x32_bf16(Al[rt][1], bh1, a, 0, 0, 0);
                acc[rt] = a;
            }

            // gate -> split -> skip B-frag directly in registers (sigma)
            short8 Bgh, Bgl;
#pragma unroll
            for (int rt = 0; rt < 2; ++rt)
#pragma unroll
                for (int r = 0; r < 4; ++r) {
                    float gated = gate_fn(acc[rt][r], acc[rt + 2][r]);
                    unsigned short hh, ll;
                    split2(gated, hh, ll);
                    Bgh[4 * rt + r] = (short)hh;
                    Bgl[4 * rt + r] = (short)ll;
                }

            f32x4 sacc[2];
#pragma unroll
            for (int rt2 = 0; rt2 < 2; ++rt2) {
                f32x4 a = bS[rt2];
                a = __builtin_amdgcn_mfma_f32_16x16x32_bf16(Sh[rt2], Bgh, a, 0, 0, 0);
                a = __builtin_amdgcn_mfma_f32_16x16x32_bf16(Sh[rt2], Bgl, a, 0, 0, 0);
                a = __builtin_amdgcn_mfma_f32_16x16x32_bf16(Sl[rt2], Bgh, a, 0, 0, 0);
                sacc[rt2] = a;
            }

            // residual: reconstruct h_old = hi+lo, add skip (ch = 16rt2+4h4+r)
#pragma unroll
            for (int rt2 = 0; rt2 < 2; ++rt2) {
                int ch = 16 * rt2 + 4 * h4;
                short4v hh = *(const short4v*)&lhi[tpos][ch];
                short4v hl = *(const short4v*)&llo[tpos][ch];
                f32x4 hv;
#pragma unroll
                for (int r = 0; r < 4; ++r)
                    hv[r] = bf2f((unsigned short)hh[r]) + bf2f((unsigned short)hl[r]);
                hnew[s6][rt2] = hv + sacc[rt2];
            }
        }
        __syncthreads();

        // ---- phase 2: split hnew once, write both planes
#pragma unroll
        for (int s6 = 0; s6 < 4; ++s6) {
            int tpos = wave * 64 + s6 * 16 + p;
#pragma unroll
            for (int rt2 = 0; rt2 < 2; ++rt2) {
                __align__(8) unsigned short oh[4], ol[4];
#pragma unroll
                for (int r = 0; r < 4; ++r)
                    split2(hnew[s6][rt2][r], oh[r], ol[r]);
                int ch = 16 * rt2 + 4 * h4;
                *(short4v*)&lhi[tpos][ch] = *(const short4v*)oh;
                *(short4v*)&llo[tpos][ch] = *(const short4v*)ol;
            }
        }
        __syncthreads();
    }

    if (!last) {
        // ---- store output rows [T0, T0+256): threads 0..255, one row each
        if (tid < 256) {
            int i = 256 + tid;
            int t = T0 + tid;
            unsigned short* dh = pout_hi + (size_t)t * CH;
            unsigned short* dl = pout_lo + (size_t)t * CH;
#pragma unroll
            for (int k = 0; k < 4; ++k) {
                *(short8*)(dh + 8 * k) = *(const short8*)&lhi[i][8 * k];
                *(short8*)(dl + 8 * k) = *(const short8*)&llo[i][8 * k];
            }
        }
    } else {
        // ---- fused finale: relu(h - h0(x)) -> Wf -> relu -> chunk-max -> atomicMax
        // red[] aliased onto dead halo rows (rows 0..12 never read post-loop)
        float* red = (float*)&lhi[0][0];
        int q = (blockIdx.x & 31) >> 3;       // 8 tiles per L/4 quarter
        if (tid < 256) {
            int i = 256 + tid;
            int t = T0 + tid;
            float xt = px[t];
            float xm = (t > 0) ? px[t - 1] : 0.0f;

            float r[CH];
#pragma unroll
            for (int c = 0; c < CH; ++c) {
                float h0 = W0[c * 2] * xm + W0[c * 2 + 1] * xt + b0[c];
                float hf = bf2f(lhi[i][c]) + bf2f(llo[i][c]);
                r[c] = fmaxf(hf - h0, 0.0f);
            }
            float y[CH];
#pragma unroll 1
            for (int o = 0; o < CH; ++o) {
                const float* w = Wf + o * CH;
                float a0 = bf[o], a1 = 0.0f, a2 = 0.0f, a3 = 0.0f;
#pragma unroll
                for (int c = 0; c < CH; c += 4) {
                    a0 += w[c + 0] * r[c + 0];
                    a1 += w[c + 1] * r[c + 1];
                    a2 += w[c + 2] * r[c + 2];
                    a3 += w[c + 3] * r[c + 3];
                }
                y[o] = fmaxf((a0 + a1) + (a2 + a3), 0.0f);
            }
#pragma unroll
            for (int o = 0; o < CH; ++o) {
#pragma unroll
                for (int off = 32; off >= 1; off >>= 1)
                    y[o] = fmaxf(y[o], __shfl_xor(y[o], off));
            }
            if (lane == 0) {
#pragma unroll
                for (int o = 0; o < CH; ++o) red[wave * CH + o] = y[o];
            }
        }
        __syncthreads();
        if (tid < CH) {
            float m = fmaxf(fmaxf(red[tid], red[CH + tid]),
                            fmaxf(red[2 * CH + tid], red[3 * CH + tid]));
            atomicMax((unsigned int*)&pooled[bb * (CH * 4) + tid * 4 + q],
                      __float_as_uint(m));
        }
    }
}

// ============ final MLP
__global__ __launch_bounds__(1024) void k_final2(const float* __restrict__ pooled,
                                                 const float* __restrict__ fW1,
                                                 const float* __restrict__ fb1,
                                                 const float* __restrict__ fW2,
                                                 const float* __restrict__ fb2,
                                                 float* __restrict__ out) {
    __shared__ float y1[BATCH * 64];
    int tid = threadIdx.x;
    int b = tid >> 6, o = tid & 63;
    float acc = fb1[o];
#pragma unroll
    for (int j = 0; j < 128; ++j) acc += fW1[o * 128 + j] * pooled[b * 128 + j];
    y1[b * 64 + o] = fmaxf(acc, 0.0f);
    __syncthreads();
    if (tid < BATCH * 10) {
        int bb = tid / 10, o2 = tid % 10;
        float a2 = fb2[o2];
#pragma unroll
        for (int j = 0; j < 64; ++j) a2 += fW2[o2 * 64 + j] * y1[bb * 64 + j];
        out[bb * 10 + o2] = a2;
    }
}

extern "C" void kernel_launch(void* const* d_in, const int* in_sizes, int n_in,
                              void* d_out, int out_size, void* d_ws, size_t ws_size,
                              hipStream_t stream) {
    const float* x   = (const float*)d_in[0];
    const float* W0  = (const float*)d_in[1];
    const float* b0  = (const float*)d_in[2];
    const float* Wd  = (const float*)d_in[3];
    const float* bd  = (const float*)d_in[4];
    const float* W1  = (const float*)d_in[5];
    const float* b1  = (const float*)d_in[6];
    const float* Wf  = (const float*)d_in[7];
    const float* bf  = (const float*)d_in[8];
    const float* fW1 = (const float*)d_in[9];
    const float* fb1 = (const float*)d_in[10];
    const float* fW2 = (const float*)d_in[11];
    const float* fb2 = (const float*)d_in[12];
    float* out = (float*)d_out;

    const size_t HS = (size_t)BATCH * SEQ * CH;        // 4M elems
    unsigned short* hiA = (unsigned short*)d_ws;       // 8 MB each plane
    unsigned short* loA = hiA + HS;
    unsigned short* hiB = loA + HS;
    unsigned short* loB = hiB + HS;
    unsigned short* wstream = loB + HS;                // 24 * 14336 shorts
    float* pooled = (float*)(wstream + (size_t)NB * 14336);

    k_prep<<<NB, 256, 0, stream>>>(Wd, bd, W1, b1, wstream, pooled);

    // stack 0: x -> B (h0 built in-LDS) ; stack 1: B -> A ; stack 2: A -> finale
    k_stack<<<512, 512, 0, stream>>>(hiA, loA, hiB, loB, x, W0, b0, Wf, bf,
                                     pooled, wstream, 0);
    k_stack<<<512, 512, 0, stream>>>(hiB, loB, hiA, loA, x, W0, b0, Wf, bf,
                                     pooled, wstream, 1);
    k_stack<<<512, 512, 0, stream>>>(hiA, loA, hiB, loB, x, W0, b0, Wf, bf,
                                     pooled, wstream, 2);

    k_final2<<<1, 1024, 0, stream>>>(pooled, fW1, fb1, fW2, fb2, out);
}

// Round 12
// 322.144 us; speedup vs baseline: 1.3890x; 1.3890x over previous
//
#include <hip/hip_runtime.h>
#include <hip/hip_bf16.h>

#define BATCH 16
#define SEQ 8192
#define CH 32
#define NB 24

typedef __attribute__((ext_vector_type(8))) short short8;
typedef __attribute__((ext_vector_type(4))) short short4v;
typedef __attribute__((ext_vector_type(4))) float f32x4;

__device__ __forceinline__ unsigned short f2bf(float x) {
    __hip_bfloat16 b = __float2bfloat16(x);   // RNE
    unsigned short u;
    __builtin_memcpy(&u, &b, 2);
    return u;
}
__device__ __forceinline__ float bf2f(unsigned short h) {
    return __uint_as_float(((unsigned int)h) << 16);
}
__device__ __forceinline__ float rcp_fast(float x) { return __builtin_amdgcn_rcpf(x); }

// tanh(f)*sigmoid(g) with a single reciprocal
__device__ __forceinline__ float gate_fn(float f, float g) {
    float ef = __expf(-2.0f * fabsf(f));
    float eg = __expf(-g);
    float num = 1.0f - ef;
    float den = (1.0f + ef) * (1.0f + eg);
    return copysignf(num * rcp_fast(den), f);
}

__device__ __forceinline__ void split2(float v, unsigned short& h, unsigned short& l) {
    h = f2bf(v);
    l = f2bf(v - bf2f(h));
}

// ============ prep (256 thr/block): bf16 hi/lo weights in MFMA frag order,
// conv rows sigma-permuted (r10: gated C-layout == skip B-layout). Zeros pooled.
__global__ __launch_bounds__(256) void k_prep(const float* __restrict__ Wd,
                                              const float* __restrict__ bd,
                                              const float* __restrict__ W1,
                                              const float* __restrict__ b1,
                                              unsigned short* __restrict__ stream,
                                              float* __restrict__ pooled) {
    int i = blockIdx.x;
    int tid = threadIdx.x;
    int l = tid & 63, q4 = tid >> 6;
    int p = l & 15, h4 = l >> 4;
    const float* wd  = Wd + (size_t)i * 64 * 64;
    const float* w1  = W1 + (size_t)i * 1024;
    const float* bdp = bd + (size_t)i * 64;
    const float* b1p = b1 + (size_t)i * 32;
    unsigned short* out = stream + (size_t)i * (28672 / 2);

    for (int g = blockIdx.x * 256 + tid; g < BATCH * CH * 4; g += NB * 256)
        pooled[g] = 0.0f;

    {   // conv A-frags: quarter q4 = tile rt
        int rt = q4;
        int is_g = (rt >= 2) ? 32 : 0;
        int ch = 8 * (p >> 2) + 4 * (rt & 1) + (p & 3);     // sigma(rt, p)
        int row = ch + is_g;
        for (int q = 0; q < 2; ++q) {
            int slot = rt * 2 + q;
            for (int j = 0; j < 8; ++j) {
                int k = 32 * q + 8 * h4 + j;
                int c = k & 31, tap = k >> 5;
                float w = wd[row * 64 + c * 2 + tap];
                unsigned short hi = f2bf(w);
                out[(size_t)slot * 512 + l * 8 + j] = hi;
                out[(size_t)(8 + slot) * 512 + l * 8 + j] = f2bf(w - bf2f(hi));
            }
        }
    }
    if (q4 < 2) {   // skip A-frags (natural order)
        int rt2 = q4;
        for (int j = 0; j < 8; ++j) {
            int o = 16 * rt2 + p, c = 8 * h4 + j;
            float w = w1[o * 32 + c];
            unsigned short hi = f2bf(w);
            out[(size_t)(16 + rt2) * 512 + l * 8 + j] = hi;
            out[(size_t)(18 + rt2) * 512 + l * 8 + j] = f2bf(w - bf2f(hi));
        }
    }
    float* outf = (float*)stream + (size_t)i * (28672 / 4);
    if (q4 == 2) {   // conv biases, sigma-permuted
        for (int rt = 0; rt < 4; ++rt) {
            int is_g = (rt >= 2) ? 32 : 0;
            for (int r = 0; r < 4; ++r)
                outf[(size_t)(20 + rt) * 256 + l * 4 + r] =
                    bdp[8 * h4 + 4 * (rt & 1) + r + is_g];
        }
    }
    if (q4 == 3) {   // skip biases (natural)
        for (int rt2 = 0; rt2 < 2; ++rt2)
            for (int r = 0; r < 4; ++r)
                outf[(size_t)(24 + rt2) * 256 + l * 4 + r] = b1p[16 * rt2 + 4 * h4 + r];
    }
}

// ============ fused 8-layer stack. r12: ONE 1024-thread block per CU.
// h in LDS as pre-split bf16 hi/lo planes (r11). W=768 rows (halo 256 + OUT 512),
// LDS = 2*768*80 = 122,880 B -> 1 block/CU, 16 waves = 4 waves/SIMD.
// Each wave owns 48 rows = 3 s6 (hnew 24 regs, was 48 in r10 / spilled in r11).
// acc-pairing: f/g tile pairs computed two-at-a-time (live acc 8 regs, not 16).
// Sigma-permuted weights (r10): skip B-frag direct in registers, no LDS bounce.
// Causal gate on GLOBAL source position (r5).
__global__ __launch_bounds__(1024, 4) void k_stack(
        const unsigned short* __restrict__ hin_hi,
        const unsigned short* __restrict__ hin_lo,
        unsigned short* __restrict__ hout_hi,
        unsigned short* __restrict__ hout_lo,
        const float* __restrict__ x,
        const float* __restrict__ W0,
        const float* __restrict__ b0,
        const float* __restrict__ Wf,
        const float* __restrict__ bf,
        float* __restrict__ pooled,
        const unsigned short* __restrict__ wstream,
        int stack) {
    __shared__ __align__(16) unsigned short lhi[768][40];   // 61,440 B
    __shared__ __align__(16) unsigned short llo[768][40];   // 61,440 B (total 122,880)

    int tid = threadIdx.x;
    int lane = tid & 63, wave = tid >> 6;
    int p = lane & 15, h4 = lane >> 4;
    int bb = blockIdx.x >> 4;                 // 16 tiles per batch
    int T0 = (blockIdx.x & 15) * 512;
    bool first = (stack == 0);
    bool last  = (stack == 2);

    const unsigned short* pin_hi = hin_hi + (size_t)bb * SEQ * CH;
    const unsigned short* pin_lo = hin_lo + (size_t)bb * SEQ * CH;
    unsigned short* pout_hi = hout_hi + (size_t)bb * SEQ * CH;
    unsigned short* pout_lo = hout_lo + (size_t)bb * SEQ * CH;
    const float* px = x + (size_t)bb * SEQ;

    const short8 zero8 = {0, 0, 0, 0, 0, 0, 0, 0};

    // ---- tile load: rows 0..767, one row per thread (tid < 768)
    if (tid < 768) {
        int i = tid;
        int t = T0 - 256 + i;
        if (first) {
            if (t >= 0) {
                float xt = px[t];
                float xm = (t > 0) ? px[t - 1] : 0.0f;
#pragma unroll
                for (int c = 0; c < CH; ++c) {
                    float v = W0[c * 2] * xm + W0[c * 2 + 1] * xt + b0[c];
                    unsigned short hh, ll;
                    split2(v, hh, ll);
                    lhi[i][c] = hh;
                    llo[i][c] = ll;
                }
            } else {
#pragma unroll
                for (int k = 0; k < 4; ++k) {
                    *(short8*)&lhi[i][8 * k] = zero8;
                    *(short8*)&llo[i][8 * k] = zero8;
                }
            }
        } else {
            if (t >= 0) {
                const unsigned short* sh = pin_hi + (size_t)t * CH;
                const unsigned short* sl = pin_lo + (size_t)t * CH;
#pragma unroll
                for (int k = 0; k < 4; ++k) {
                    *(short8*)&lhi[i][8 * k] = *(const short8*)(sh + 8 * k);
                    *(short8*)&llo[i][8 * k] = *(const short8*)(sl + 8 * k);
                }
            } else {
#pragma unroll
                for (int k = 0; k < 4; ++k) {
                    *(short8*)&lhi[i][8 * k] = zero8;
                    *(short8*)&llo[i][8 * k] = zero8;
                }
            }
        }
    }
    __syncthreads();

#pragma unroll 1
    for (int l = 0; l < 8; ++l) {
        int dil = 1 << l;
        const unsigned short* frag = wstream + (size_t)(8 * stack + l) * 14336;
        const short8* fs = (const short8*)frag;
        short8 Ah[4][2], Al[4][2], Sh[2], Sl[2];
#pragma unroll
        for (int rt = 0; rt < 4; ++rt)
#pragma unroll
            for (int q = 0; q < 2; ++q) {
                Ah[rt][q] = fs[(rt * 2 + q) * 64 + lane];
                Al[rt][q] = fs[(8 + rt * 2 + q) * 64 + lane];
            }
#pragma unroll
        for (int rt2 = 0; rt2 < 2; ++rt2) {
            Sh[rt2] = fs[(16 + rt2) * 64 + lane];
            Sl[rt2] = fs[(18 + rt2) * 64 + lane];
        }
        const f32x4* ff = (const f32x4*)frag;
        f32x4 bFG[4], bS[2];
#pragma unroll
        for (int rt = 0; rt < 4; ++rt) bFG[rt] = ff[(20 + rt) * 64 + lane];
#pragma unroll
        for (int rt2 = 0; rt2 < 2; ++rt2) bS[rt2] = ff[(24 + rt2) * 64 + lane];

        f32x4 hnew[3][2];

        // ---- phase 1: 3 s6 per wave; conv frags are raw b128 reads
#pragma unroll
        for (int s6 = 0; s6 < 3; ++s6) {
            int tpos = wave * 48 + s6 * 16 + p;
            int tq = tpos - dil;
            bool ok = (T0 - 256 + tq >= 0);   // causal gate on GLOBAL source pos
            int tqc = (tq > 0) ? tq : 0;

            short8 bh1 = *(const short8*)&lhi[tpos][8 * h4];
            short8 bl1 = *(const short8*)&llo[tpos][8 * h4];
            short8 bh0 = *(const short8*)&lhi[tqc][8 * h4];
            short8 bl0 = *(const short8*)&llo[tqc][8 * h4];
            if (!ok) { bh0 = zero8; bl0 = zero8; }

            // acc-pairing: compute (f-half, g-half) together, gate, release regs
            short8 Bgh, Bgl;
#pragma unroll
            for (int half = 0; half < 2; ++half) {
                f32x4 af = bFG[half];
                f32x4 ag = bFG[half + 2];
                af = __builtin_amdgcn_mfma_f32_16x16x32_bf16(Ah[half][0], bh0, af, 0, 0, 0);
                ag = __builtin_amdgcn_mfma_f32_16x16x32_bf16(Ah[half + 2][0], bh0, ag, 0, 0, 0);
                af = __builtin_amdgcn_mfma_f32_16x16x32_bf16(Ah[half][1], bh1, af, 0, 0, 0);
                ag = __builtin_amdgcn_mfma_f32_16x16x32_bf16(Ah[half + 2][1], bh1, ag, 0, 0, 0);
                af = __builtin_amdgcn_mfma_f32_16x16x32_bf16(Ah[half][0], bl0, af, 0, 0, 0);
                ag = __builtin_amdgcn_mfma_f32_16x16x32_bf16(Ah[half + 2][0], bl0, ag, 0, 0, 0);
                af = __builtin_amdgcn_mfma_f32_16x16x32_bf16(Ah[half][1], bl1, af, 0, 0, 0);
                ag = __builtin_amdgcn_mfma_f32_16x16x32_bf16(Ah[half + 2][1], bl1, ag, 0, 0, 0);
                af = __builtin_amdgcn_mfma_f32_16x16x32_bf16(Al[half][0], bh0, af, 0, 0, 0);
                ag = __builtin_amdgcn_mfma_f32_16x16x32_bf16(Al[half + 2][0], bh0, ag, 0, 0, 0);
                af = __builtin_amdgcn_mfma_f32_16x16x32_bf16(Al[half][1], bh1, af, 0, 0, 0);
                ag = __builtin_amdgcn_mfma_f32_16x16x32_bf16(Al[half + 2][1], bh1, ag, 0, 0, 0);
#pragma unroll
                for (int r = 0; r < 4; ++r) {
                    float gated = gate_fn(af[r], ag[r]);
                    unsigned short hh, ll;
                    split2(gated, hh, ll);
                    Bgh[4 * half + r] = (short)hh;
                    Bgl[4 * half + r] = (short)ll;
                }
            }

            f32x4 sacc[2];
#pragma unroll
            for (int rt2 = 0; rt2 < 2; ++rt2) {
                f32x4 a = bS[rt2];
                a = __builtin_amdgcn_mfma_f32_16x16x32_bf16(Sh[rt2], Bgh, a, 0, 0, 0);
                a = __builtin_amdgcn_mfma_f32_16x16x32_bf16(Sh[rt2], Bgl, a, 0, 0, 0);
                a = __builtin_amdgcn_mfma_f32_16x16x32_bf16(Sl[rt2], Bgh, a, 0, 0, 0);
                sacc[rt2] = a;
            }

            // residual: reconstruct h_old = hi+lo, add skip (ch = 16rt2+4h4+r)
#pragma unroll
            for (int rt2 = 0; rt2 < 2; ++rt2) {
                int ch = 16 * rt2 + 4 * h4;
                short4v hh = *(const short4v*)&lhi[tpos][ch];
                short4v hl = *(const short4v*)&llo[tpos][ch];
                f32x4 hv;
#pragma unroll
                for (int r = 0; r < 4; ++r)
                    hv[r] = bf2f((unsigned short)hh[r]) + bf2f((unsigned short)hl[r]);
                hnew[s6][rt2] = hv + sacc[rt2];
            }
        }
        __syncthreads();

        // ---- phase 2: split hnew once, write both planes
#pragma unroll
        for (int s6 = 0; s6 < 3; ++s6) {
            int tpos = wave * 48 + s6 * 16 + p;
#pragma unroll
            for (int rt2 = 0; rt2 < 2; ++rt2) {
                __align__(8) unsigned short oh[4], ol[4];
#pragma unroll
                for (int r = 0; r < 4; ++r)
                    split2(hnew[s6][rt2][r], oh[r], ol[r]);
                int ch = 16 * rt2 + 4 * h4;
                *(short4v*)&lhi[tpos][ch] = *(const short4v*)oh;
                *(short4v*)&llo[tpos][ch] = *(const short4v*)ol;
            }
        }
        __syncthreads();
    }

    if (!last) {
        // ---- store output rows [T0, T0+512): threads 0..511, one row each
        if (tid < 512) {
            int i = 256 + tid;
            int t = T0 + tid;
            unsigned short* dh = pout_hi + (size_t)t * CH;
            unsigned short* dl = pout_lo + (size_t)t * CH;
#pragma unroll
            for (int k = 0; k < 4; ++k) {
                *(short8*)(dh + 8 * k) = *(const short8*)&lhi[i][8 * k];
                *(short8*)(dl + 8 * k) = *(const short8*)&llo[i][8 * k];
            }
        }
    } else {
        // ---- fused finale: relu(h - h0(x)) -> Wf -> relu -> chunk-max -> atomicMax
        // red[] aliased onto dead halo rows (rows 0..12 never read after last layer)
        float* red = (float*)&lhi[0][0];
        int q = (blockIdx.x & 15) >> 2;       // 4 tiles per L/4 quarter
        if (tid < 512) {
            int i = 256 + tid;
            int t = T0 + tid;
            float xt = px[t];
            float xm = (t > 0) ? px[t - 1] : 0.0f;

            float r[CH];
#pragma unroll
            for (int c = 0; c < CH; ++c) {
                float h0 = W0[c * 2] * xm + W0[c * 2 + 1] * xt + b0[c];
                float hf = bf2f(lhi[i][c]) + bf2f(llo[i][c]);
                r[c] = fmaxf(hf - h0, 0.0f);
            }
            float y[CH];
#pragma unroll 1
            for (int o = 0; o < CH; ++o) {
                const float* w = Wf + o * CH;
                float a0 = bf[o], a1 = 0.0f, a2 = 0.0f, a3 = 0.0f;
#pragma unroll
                for (int c = 0; c < CH; c += 4) {
                    a0 += w[c + 0] * r[c + 0];
                    a1 += w[c + 1] * r[c + 1];
                    a2 += w[c + 2] * r[c + 2];
                    a3 += w[c + 3] * r[c + 3];
                }
                y[o] = fmaxf((a0 + a1) + (a2 + a3), 0.0f);
            }
#pragma unroll
            for (int o = 0; o < CH; ++o) {
#pragma unroll
                for (int off = 32; off >= 1; off >>= 1)
                    y[o] = fmaxf(y[o], __shfl_xor(y[o], off));
            }
            if (lane == 0) {
#pragma unroll
                for (int o = 0; o < CH; ++o) red[wave * CH + o] = y[o];
            }
        }
        __syncthreads();
        if (tid < CH) {
            float m = red[tid];
#pragma unroll
            for (int w8 = 1; w8 < 8; ++w8) m = fmaxf(m, red[w8 * CH + tid]);
            atomicMax((unsigned int*)&pooled[bb * (CH * 4) + tid * 4 + q],
                      __float_as_uint(m));
        }
    }
}

// ============ final MLP
__global__ __launch_bounds__(1024) void k_final2(const float* __restrict__ pooled,
                                                 const float* __restrict__ fW1,
                                                 const float* __restrict__ fb1,
                                                 const float* __restrict__ fW2,
                                                 const float* __restrict__ fb2,
                                                 float* __restrict__ out) {
    __shared__ float y1[BATCH * 64];
    int tid = threadIdx.x;
    int b = tid >> 6, o = tid & 63;
    float acc = fb1[o];
#pragma unroll
    for (int j = 0; j < 128; ++j) acc += fW1[o * 128 + j] * pooled[b * 128 + j];
    y1[b * 64 + o] = fmaxf(acc, 0.0f);
    __syncthreads();
    if (tid < BATCH * 10) {
        int bb = tid / 10, o2 = tid % 10;
        float a2 = fb2[o2];
#pragma unroll
        for (int j = 0; j < 64; ++j) a2 += fW2[o2 * 64 + j] * y1[bb * 64 + j];
        out[bb * 10 + o2] = a2;
    }
}

extern "C" void kernel_launch(void* const* d_in, const int* in_sizes, int n_in,
                              void* d_out, int out_size, void* d_ws, size_t ws_size,
                              hipStream_t stream) {
    const float* x   = (const float*)d_in[0];
    const float* W0  = (const float*)d_in[1];
    const float* b0  = (const float*)d_in[2];
    const float* Wd  = (const float*)d_in[3];
    const float* bd  = (const float*)d_in[4];
    const float* W1  = (const float*)d_in[5];
    const float* b1  = (const float*)d_in[6];
    const float* Wf  = (const float*)d_in[7];
    const float* bf  = (const float*)d_in[8];
    const float* fW1 = (const float*)d_in[9];
    const float* fb1 = (const float*)d_in[10];
    const float* fW2 = (const float*)d_in[11];
    const float* fb2 = (const float*)d_in[12];
    float* out = (float*)d_out;

    const size_t HS = (size_t)BATCH * SEQ * CH;        // 4M elems
    unsigned short* hiA = (unsigned short*)d_ws;       // 8 MB each plane
    unsigned short* loA = hiA + HS;
    unsigned short* hiB = loA + HS;
    unsigned short* loB = hiB + HS;
    unsigned short* wstream = loB + HS;                // 24 * 14336 shorts
    float* pooled = (float*)(wstream + (size_t)NB * 14336);

    k_prep<<<NB, 256, 0, stream>>>(Wd, bd, W1, b1, wstream, pooled);

    // stack 0: x -> B (h0 built in-LDS) ; stack 1: B -> A ; stack 2: A -> finale
    k_stack<<<256, 1024, 0, stream>>>(hiA, loA, hiB, loB, x, W0, b0, Wf, bf,
                                      pooled, wstream, 0);
    k_stack<<<256, 1024, 0, stream>>>(hiB, loB, hiA, loA, x, W0, b0, Wf, bf,
                                      pooled, wstream, 1);
    k_stack<<<256, 1024, 0, stream>>>(hiA, loA, hiB, loB, x, W0, b0, Wf, bf,
                                      pooled, wstream, 2);

    k_final2<<<1, 1024, 0, stream>>>(pooled, fW1, fb1, fW2, fb2, out);
}